// Round 1
// 1151.391 us; speedup vs baseline: 1.0271x; 1.0271x over previous
//
#include <hip/hip_runtime.h>

#define N_NODES 100000
#define N_EDGES 1638400
#define IN_CH   128
#define HEADS   4
#define OUT_CH  32
#define HC      (HEADS * OUT_CH)   // 128

typedef float f4 __attribute__((ext_vector_type(4)));

// ---------------------------------------------------------------------------
// Kernel 1: h = x @ W^T + b  (fp32 vector ALU — no fp32 MFMA on CDNA4)
// FUSED: per-node attention scores alpha_l/alpha_r (kills old kernel 2).
//
// Tile: 64 nodes x 128 cols per block, 256 threads.
// Thread (c = t&31, g = t>>5) computes 8 nodes (g*8..g*8+7) x 4 cols
// {c, c+32, c+64, c+96} — one col per head, so the alpha dot product's
// reduction axis (out-ch) lies across the 32 lanes of a half-wave.
//
// LDS cut vs previous version: W staged in TWO 64-k chunks (33 KB buffer
// instead of 66 KB). Total LDS 65,792 B -> 2 blocks/CU (8 waves/CU) instead
// of 1 block (4 waves, 1 wave/SIMD, zero latency hiding).
// sWt stride 129: transpose writes and compute reads both conflict-free.
// ---------------------------------------------------------------------------
__launch_bounds__(256, 2)
__global__ void gat_gemm_kernel(const float* __restrict__ x,
                                const float* __restrict__ W,
                                const float* __restrict__ bias,
                                const float* __restrict__ att_l,
                                const float* __restrict__ att_r,
                                float* __restrict__ h,
                                float* __restrict__ al,
                                float* __restrict__ ar, int n) {
    __shared__ float sWt[64 * 129];   // 33,024 B (one 64-k chunk, transposed)
    __shared__ float sX[64 * 128];    // 32,768 B   (total 65,792 B)

    const int t = threadIdx.x;
    const int node_base = blockIdx.x * 64;
    const int c = t & 31;
    const int g = t >> 5;

    // Stage x tile as float4 (rows contiguous: 64 rows x 512 B)
    {
        const f4* x4 = (const f4*)(x + (size_t)node_base * IN_CH);
        f4* sX4 = (f4*)sX;
        int rows = n - node_base;     // may be < 64 for last block
        for (int i = t; i < 64 * 32; i += 256) {
            int row = i >> 5;
            f4 v = {0.f, 0.f, 0.f, 0.f};
            if (row < rows) v = x4[i];
            sX4[i] = v;
        }
    }

    float acc[8][4];
    #pragma unroll
    for (int i = 0; i < 8; ++i)
        #pragma unroll
        for (int j = 0; j < 4; ++j) acc[i][j] = 0.f;

    const f4* W4 = (const f4*)W;

    for (int kb = 0; kb < 128; kb += 64) {
        __syncthreads();   // protect sWt reuse (covers initial sX publish too)

        // Stage W chunk: o = 0..127 rows, k = kb..kb+63, float4 global reads.
        // Transposed write sWt[(4j+m)*129+o]: banks (4j+m+o)%32 across a
        // wave = all 32 banks 2-way -> free (m136).
        #pragma unroll
        for (int i = 0; i < 8; ++i) {
            int idx = i * 256 + t;            // 0..2047
            int o = idx >> 4, j = idx & 15;
            f4 w = W4[o * 32 + (kb >> 2) + j];
            sWt[(4 * j + 0) * 129 + o] = w.x;
            sWt[(4 * j + 1) * 129 + o] = w.y;
            sWt[(4 * j + 2) * 129 + o] = w.z;
            sWt[(4 * j + 3) * 129 + o] = w.w;
        }
        __syncthreads();

        #pragma unroll 4
        for (int kl = 0; kl < 64; ++kl) {
            int k = kb + kl;
            float w0 = sWt[kl * 129 + c];
            float w1 = sWt[kl * 129 + c + 32];
            float w2 = sWt[kl * 129 + c + 64];
            float w3 = sWt[kl * 129 + c + 96];
            #pragma unroll
            for (int i = 0; i < 8; ++i) {
                float xv = sX[(g * 8 + i) * 128 + k];   // broadcast read
                acc[i][0] += xv * w0;
                acc[i][1] += xv * w1;
                acc[i][2] += xv * w2;
                acc[i][3] += xv * w3;
            }
        }
    }

    // Epilogue: bias, h store, fused alpha_l/alpha_r reduction.
    const float b0 = bias[c], b1 = bias[c + 32], b2 = bias[c + 64], b3 = bias[c + 96];
    const float l0 = att_l[c], l1 = att_l[c + 32], l2 = att_l[c + 64], l3 = att_l[c + 96];
    const float r0 = att_r[c], r1 = att_r[c + 32], r2 = att_r[c + 64], r3 = att_r[c + 96];

    #pragma unroll
    for (int i = 0; i < 8; ++i) {
        int node = node_base + g * 8 + i;
        float h0 = acc[i][0] + b0;
        float h1 = acc[i][1] + b1;
        float h2 = acc[i][2] + b2;
        float h3 = acc[i][3] + b3;
        if (node < n) {
            float* hp = h + (size_t)node * HC;
            hp[c]      = h0;
            hp[c + 32] = h1;
            hp[c + 64] = h2;
            hp[c + 96] = h3;
        }
        // per-(node,head) dot with att vectors; reduce over the 32 lanes (c)
        float pl0 = l0 * h0, pl1 = l1 * h1, pl2 = l2 * h2, pl3 = l3 * h3;
        float pr0 = r0 * h0, pr1 = r1 * h1, pr2 = r2 * h2, pr3 = r3 * h3;
        #pragma unroll
        for (int off = 16; off; off >>= 1) {
            pl0 += __shfl_xor(pl0, off);
            pl1 += __shfl_xor(pl1, off);
            pl2 += __shfl_xor(pl2, off);
            pl3 += __shfl_xor(pl3, off);
            pr0 += __shfl_xor(pr0, off);
            pr1 += __shfl_xor(pr1, off);
            pr2 += __shfl_xor(pr2, off);
            pr3 += __shfl_xor(pr3, off);
        }
        if (c == 0 && node < n) {
            f4 va = {pl0, pl1, pl2, pl3};
            f4 vb = {pr0, pr1, pr2, pr3};
            *(f4*)(al + (size_t)node * HEADS) = va;
            *(f4*)(ar + (size_t)node * HEADS) = vb;
        }
    }
}

// ---------------------------------------------------------------------------
// Kernel 2: edge gather — HBM-write-bound (~865 MB writes).
// 32 lanes per edge; each lane copies one float4 of the 128-float h row.
// NON-TEMPORAL stores on all outputs: the 865 MB write stream must not
// allocate in L2, so the random h/al/ar gathers keep their L2 residency.
// nt loads on the once-streamed index arrays for the same reason.
// ---------------------------------------------------------------------------
__launch_bounds__(256)
__global__ void gat_edge_kernel(const int* __restrict__ src_idx,
                                const int* __restrict__ trg_idx,
                                const float* __restrict__ h,
                                const float* __restrict__ al,
                                const float* __restrict__ ar,
                                float* __restrict__ out_alpha,
                                float* __restrict__ out_x) {
    int tid = blockIdx.x * 256 + threadIdx.x;
    int e = tid >> 5;            // grid sized exactly: e < N_EDGES always
    int lane = tid & 31;

    int src = __builtin_nontemporal_load(src_idx + e);

    // x_lifted copy: 512 B per edge, contiguous across lanes & edges
    f4 v = *(const f4*)(h + (size_t)src * HC + lane * 4);
    __builtin_nontemporal_store(v, (f4*)(out_x + (size_t)e * HC + lane * 4));

    if (lane == 0) {
        int trg = __builtin_nontemporal_load(trg_idx + e);
        f4 a = *(const f4*)(al + (size_t)src * HEADS);
        f4 b = *(const f4*)(ar + (size_t)trg * HEADS);
        f4 o;
        float s;
        s = a.x + b.x; o.x = s > 0.f ? s : 0.01f * s;
        s = a.y + b.y; o.y = s > 0.f ? s : 0.01f * s;
        s = a.z + b.z; o.z = s > 0.f ? s : 0.01f * s;
        s = a.w + b.w; o.w = s > 0.f ? s : 0.01f * s;
        __builtin_nontemporal_store(o, (f4*)(out_alpha + (size_t)e * HEADS));
    }
}

// ---------------------------------------------------------------------------
extern "C" void kernel_launch(void* const* d_in, const int* in_sizes, int n_in,
                              void* d_out, int out_size, void* d_ws, size_t ws_size,
                              hipStream_t stream) {
    const float* x     = (const float*)d_in[0];
    const float* W     = (const float*)d_in[1];
    const float* bias  = (const float*)d_in[2];
    const float* att_l = (const float*)d_in[3];
    const float* att_r = (const float*)d_in[4];
    const int* src_idx = (const int*)d_in[5];
    const int* trg_idx = (const int*)d_in[6];

    // Workspace layout (fp32): h [N,128] | alpha_l [N,4] | alpha_r [N,4]
    float* h  = (float*)d_ws;                                  // 51,200,000 B
    float* al = h + (size_t)N_NODES * HC;                      // +1,600,000 B
    float* ar = al + (size_t)N_NODES * HEADS;                  // +1,600,000 B

    // Outputs: alpha_per_edge [E,4] then x_lifted [E,4,32], concatenated flat
    float* out_alpha = (float*)d_out;
    float* out_x     = out_alpha + (size_t)N_EDGES * HEADS;

    // 1) projection + fused per-node scores
    int gemm_blocks = (N_NODES + 63) / 64;                     // 1563
    gat_gemm_kernel<<<gemm_blocks, 256, 0, stream>>>(x, W, bias, att_l, att_r,
                                                     h, al, ar, N_NODES);

    // 2) edge gather
    int edge_blocks = (N_EDGES * 32) / 256;                    // 204800
    gat_edge_kernel<<<edge_blocks, 256, 0, stream>>>(src_idx, trg_idx, h, al, ar,
                                                     out_alpha, out_x);
}